// Round 7
// baseline (157.553 us; speedup 1.0000x reference)
//
#include <hip/hip_runtime.h>
#include <hip/hip_bf16.h>
#include <math.h>

typedef __bf16 bf16;
typedef __bf16 bf16x8 __attribute__((ext_vector_type(8)));
typedef float  f32x4  __attribute__((ext_vector_type(4)));

#define NTOK   16384
#define DIN    512
#define DOUT   512
#define NTYPES 128
#define TEBD   128
#define NEXP   8
#define NPAIR  64      // pair key = e0*8+e1 (e0 = top-1, e1 = top-2, always distinct)
#define MAXTILE 192    // sum_l ceil(n_l/128) <= 64 + 16384/128 = 192

// ---- workspace layout (bytes); total ~21.3 MB ----
#define WS_HPART   0                          // int[128][64] per-type,per-block hist (32KB, transposed)
#define WS_ROUTE_W 32768                      // float2[128] (w0,w1) per type
#define WS_BASET   33792                      // int[128]   packed base per type
#define WS_CURS    34304                      // int[128]   per-type cursor
#define WS_CNTP    34816                      // int[64]    per-pair count
#define WS_BASEP   35072                      // int[64]    per-pair base
#define WS_NTILE   35328                      // int[1]
#define WS_TMAP    35840                      // int2[192] (list, r0)
#define WS_RMAP    37888                      // int[16384] packed row -> token
#define WS_WGT     (WS_RMAP + NTOK * 4)       // float2[16384] packed row -> (w0,w1)
#define WS_XG      (WS_WGT + NTOK * 8)        // bf16[16384*512] pair-sorted x (16 MB)
#define WS_WET     (WS_XG + (size_t)NTOK * DIN * 2)  // bf16[8*512*512] (4 MB)

// ------- per-block type histogram partials, TRANSPOSED [type][block] -------
// (no memset, no global atomics; route_scan reduces 64 contiguous ints/type)
__global__ void hist_kernel(const int* __restrict__ atype, int* __restrict__ hpart) {
  __shared__ int h[NTYPES];
  int tid = threadIdx.x;
  if (tid < NTYPES) h[tid] = 0;
  __syncthreads();
  int t = blockIdx.x * 256 + tid;
  atomicAdd(&h[atype[t]], 1);
  __syncthreads();
  if (tid < NTYPES) hpart[tid * 64 + blockIdx.x] = h[tid];
}

// ---- route (top-2 softmax per type) + pair scan + tile map, one block -----
// Tokens of one type all map to one pair, so each type gets a CONTIGUOUS
// subrange inside its pair list: base_type[t] = base_pair[p_t] + within-pair
// offset. Placement then needs only a per-type cursor (no second scan pass).
__global__ void route_scan_kernel(const float* __restrict__ emb,
                                  const float* __restrict__ Wg,
                                  const int* __restrict__ hpart,
                                  float* __restrict__ route_w,
                                  int* __restrict__ base_type,
                                  int* __restrict__ cursor,
                                  int* __restrict__ cnt_pair,
                                  int* __restrict__ base_pair,
                                  int* __restrict__ ntile,
                                  int* __restrict__ tmap) {
  __shared__ int s_cnt[NPAIR];
  __shared__ int s_off[NTYPES];
  __shared__ int s_pair[NTYPES];
  int t = threadIdx.x;  // 128 threads = 128 types
  if (t < NPAIR) s_cnt[t] = 0;
  __syncthreads();

  // reduce the 64 per-block hist partials for this type: 16 independent
  // int4 loads from a contiguous 256B range (latency-overlapped)
  int myc = 0;
  {
    const int4* hp = (const int4*)(hpart + t * 64);
#pragma unroll
    for (int b = 0; b < 16; ++b) {
      int4 v = hp[b];
      myc += v.x + v.y + v.z + v.w;
    }
  }

  const float* er = emb + (size_t)t * TEBD;
  float lg[NEXP];
#pragma unroll
  for (int e = 0; e < NEXP; ++e) lg[e] = 0.f;
  for (int j = 0; j < TEBD; ++j) {
    float ev = er[j];
#pragma unroll
    for (int e = 0; e < NEXP; ++e) lg[e] += ev * Wg[j * NEXP + e];
  }
  float v0 = -__builtin_inff(), v1 = -__builtin_inff();
  int i0 = 0, i1 = 0;
#pragma unroll
  for (int e = 0; e < NEXP; ++e) {
    float v = lg[e];
    if (v > v0) { v1 = v0; i1 = i0; v0 = v; i0 = e; }
    else if (v > v1) { v1 = v; i1 = e; }
  }
  float d = expf(v1 - v0);
  float inv = 1.f / (1.f + d);
  route_w[t * 2 + 0] = inv;
  route_w[t * 2 + 1] = d * inv;
  int p = i0 * 8 + i1;
  s_pair[t] = p;
  s_off[t] = atomicAdd(&s_cnt[p], myc);  // within-pair offset (any order ok)
  cursor[t] = 0;
  __syncthreads();

  if (t < NPAIR) {
    int b = 0, tb = 0;
    for (int j = 0; j < t; ++j) { b += s_cnt[j]; tb += (s_cnt[j] + 127) >> 7; }
    base_pair[t] = b;
    cnt_pair[t] = s_cnt[t];
    int nt_l = (s_cnt[t] + 127) >> 7;
    for (int i = 0; i < nt_l; ++i) {
      tmap[(tb + i) * 2 + 0] = t;
      tmap[(tb + i) * 2 + 1] = i * 128;
    }
    if (t == NPAIR - 1) ntile[0] = tb + nt_l;
  }
  __syncthreads();
  base_type[t] = base_pair[s_pair[t]] + s_off[t];
}

// ---- fused prep: place+gather+cvt (blocks 0..255) | WeT^T (blocks 256..767)
__global__ void prep_kernel(const float* __restrict__ x,
                            const float* __restrict__ We,
                            const int* __restrict__ atype,
                            const float* __restrict__ route_w,
                            const int* __restrict__ base_type,
                            int* __restrict__ cursor,
                            int* __restrict__ row_map,
                            float* __restrict__ wgt,
                            bf16* __restrict__ xg,
                            bf16* __restrict__ WeT) {
  int bx = blockIdx.x;
  int tid = threadIdx.x;
  if (bx < 256) {
    // ---- place + gather-convert 64 tokens ----
    __shared__ int posS[64];
    int t0 = bx * 64;
    if (tid < 64) {
      int t = t0 + tid;
      int ty = atype[t];
      int pos = base_type[ty] + atomicAdd(&cursor[ty], 1);
      posS[tid] = pos;
      row_map[pos] = t;
      ((float2*)wgt)[pos] = ((const float2*)route_w)[ty];
    }
    __syncthreads();
    int w = tid >> 6, lane = tid & 63;
#pragma unroll
    for (int i = 0; i < 16; ++i) {
      int r = w * 16 + i;
      const float4* p = (const float4*)(x + (size_t)(t0 + r) * DIN + lane * 8);
      float4 a = p[0], b = p[1];
      bf16x8 o;
      o[0] = (bf16)a.x; o[1] = (bf16)a.y; o[2] = (bf16)a.z; o[3] = (bf16)a.w;
      o[4] = (bf16)b.x; o[5] = (bf16)b.y; o[6] = (bf16)b.z; o[7] = (bf16)b.w;
      *(bf16x8*)(xg + (size_t)posS[r] * DIN + lane * 8) = o;
    }
  } else {
    // ---- We[e][k][n] f32 -> WeT[e][n][k] bf16, 64x64 tiles ----
    __shared__ float t[64][65];
    int b2 = bx - 256;        // 512 = 8 experts * 8 * 8 tiles
    int e = b2 >> 6;
    int rem = b2 & 63;
    int kt = (rem >> 3) * 64;
    int nt = (rem & 7) * 64;
    int col = tid & 63;
    int rq = tid >> 6;
#pragma unroll
    for (int r = 0; r < 16; ++r) {
      int row = rq * 16 + r;
      t[row][col] = We[((size_t)e * DIN + kt + row) * DOUT + nt + col];
    }
    __syncthreads();
#pragma unroll
    for (int r = 0; r < 16; ++r) {
      int n = rq * 16 + r;
      WeT[((size_t)e * DOUT + nt + n) * DIN + kt + col] = (bf16)t[col][n];
    }
  }
}

// --------- pair-merged grouped GEMM: NO-LDS register-direct version --------
// Round-7 theory: at 47us every pipe was <=25% busy and depth/tile changes
// were flat -> the barrier-lockstep chain (vmcnt -> s_barrier -> ds_read ->
// lgkmcnt -> MFMA, x16 per block) was the wall, ~3000cy/iter of mostly
// serial latency. K=512 operands are cache-resident (WeT 4MB in L2, xg
// 16MB in L3, XCD-swizzled for locality), and both MFMA fragments are 16B
// contiguous per lane in memory. So: load fragments DIRECTLY to registers
// (global_load_dwordx4 with compile-time offsets), register-double-buffer
// 2 k-steps, zero barriers in the main loop, zero LDS staging. Waves slide
// freely; compiler inserts exact per-load waitcnts. Redundant fragment
// pairs (waves 0/1 share A rows, 0/2 share B cols) coalesce in L1.
// tile: BM=128 x BN=64 x 2 experts, 4 waves (2x2), 16 MFMA/wave/iter.
// VGPR ~164 -> 3 waves/SIMD (was 2 with 64KB LDS).
__global__ __launch_bounds__(256, 3) void moe_gemm_pair_kernel(
    const bf16* __restrict__ xg, const bf16* __restrict__ WeT,
    const float* __restrict__ be, const int* __restrict__ cnt_pair,
    const int* __restrict__ base_pair, const int* __restrict__ ntile,
    const int* __restrict__ tmap, const int* __restrict__ row_map,
    const float* __restrict__ wgt, float* __restrict__ out) {
  int nwork = ntile[0] * 8;
  int f = blockIdx.y * 8 + blockIdx.x;
  if (f >= nwork) return;
  // bijective chunked XCD swizzle over the working range: logical tile L
  // (row-tile-major, 8 col blocks adjacent) -> contiguous chunk per XCD,
  // so same-list A rows and B panels stay L2-local.
  int q = nwork >> 3, r = nwork & 7;
  int xcd = f & 7, idx = f >> 3;
  int L = (xcd < r ? xcd * (q + 1) : r * (q + 1) + (xcd - r) * q) + idx;
  int ti = L >> 3;
  int cx = L & 7;
  int list = tmap[ti * 2 + 0];
  int r0   = tmap[ti * 2 + 1];
  int e0 = list >> 3, e1 = list & 7;
  int nrow = cnt_pair[list] - r0;
  if (nrow > 128) nrow = 128;
  int c0 = cx * 64;
  int arow0 = base_pair[list] + r0;

  __shared__ int   tokS[128];
  __shared__ float w0S[128], w1S[128];
  __shared__ float be0S[64], be1S[64];

  int tid = threadIdx.x;
  int lane = tid & 63, w = tid >> 6;

  // epilogue metadata -> LDS (one barrier before epilogue orders it)
  if (tid < 128) {
    int srow = (tid < nrow) ? tid : (nrow - 1);
    int gl = arow0 + srow;
    tokS[tid] = row_map[gl];
    float2 ww = ((const float2*)wgt)[gl];
    w0S[tid] = ww.x;
    w1S[tid] = ww.y;
    if (tid < 64) {
      be0S[tid] = be[e0 * DOUT + c0 + tid];
      be1S[tid] = be[e1 * DOUT + c0 + tid];
    }
  }

  int wm = (w >> 1) * 64;
  int wn = (w & 1) * 32;
  int r16 = lane & 15, g16 = lane >> 4;

  // per-lane fragment base pointers; k-step t adds a compile-time t*64B
  // offset (fits global_load's signed 13-bit imm) -> zero per-iter VALU.
  // A frag lane layout for mfma_16x16x32: row = base+(lane&15), k-half =
  // (lane>>4)*8; 16B contiguous along K in xg[row][k]. B identical in WeT.
  const bf16* pA[4];
#pragma unroll
  for (int i = 0; i < 4; ++i) {
    int rowA = wm + i * 16 + r16;
    int srow = (rowA < nrow) ? rowA : (nrow - 1);
    pA[i] = xg + (size_t)(arow0 + srow) * DIN + g16 * 8;
  }
  const bf16* pB0[2];
  const bf16* pB1[2];
#pragma unroll
  for (int i = 0; i < 2; ++i) {
    int colB = wn + i * 16 + r16;
    pB0[i] = WeT + ((size_t)e0 * DOUT + c0 + colB) * DIN + g16 * 8;
    pB1[i] = WeT + ((size_t)e1 * DOUT + c0 + colB) * DIN + g16 * 8;
  }

  f32x4 acc0[4][2], acc1[4][2];
#pragma unroll
  for (int mi = 0; mi < 4; ++mi)
#pragma unroll
    for (int ni = 0; ni < 2; ++ni) { acc0[mi][ni] = (f32x4)0.f; acc1[mi][ni] = (f32x4)0.f; }

  // two register fragment sets, ping-pong over k-steps (static indexing only)
  bf16x8 aX[4], b0X[2], b1X[2];
  bf16x8 aY[4], b0Y[2], b1Y[2];

#define LOADSET(A, B0, B1, kk)                                                \
  {                                                                           \
    _Pragma("unroll") for (int i = 0; i < 4; ++i)                             \
        A[i] = *(const bf16x8*)(pA[i] + (kk) * 32);                           \
    _Pragma("unroll") for (int i = 0; i < 2; ++i)                             \
        B0[i] = *(const bf16x8*)(pB0[i] + (kk) * 32);                         \
    _Pragma("unroll") for (int i = 0; i < 2; ++i)                             \
        B1[i] = *(const bf16x8*)(pB1[i] + (kk) * 32);                         \
  }

#define MFMASET(A, B0, B1)                                                    \
  {                                                                           \
    _Pragma("unroll") for (int mi = 0; mi < 4; ++mi)                          \
        _Pragma("unroll") for (int ni = 0; ni < 2; ++ni) {                    \
      acc0[mi][ni] = __builtin_amdgcn_mfma_f32_16x16x32_bf16(                 \
          A[mi], B0[ni], acc0[mi][ni], 0, 0, 0);                              \
      acc1[mi][ni] = __builtin_amdgcn_mfma_f32_16x16x32_bf16(                 \
          A[mi], B1[ni], acc1[mi][ni], 0, 0, 0);                              \
    }                                                                         \
  }

  LOADSET(aX, b0X, b1X, 0);
  LOADSET(aY, b0Y, b1Y, 1);
#pragma unroll
  for (int t = 0; t < 16; t += 2) {
    MFMASET(aX, b0X, b1X);
    if (t + 2 < 16) LOADSET(aX, b0X, b1X, t + 2);
    MFMASET(aY, b0Y, b1Y);
    if (t + 3 < 16) LOADSET(aY, b0Y, b1Y, t + 3);
  }
#undef LOADSET
#undef MFMASET

  __syncthreads();  // order the tokS/wS/beS writes before epilogue reads

  // ---- epilogue: out = w0*tanh(acc0+b0) + w1*tanh(acc1+b1), plain store ---
  // fast tanh: tanh(x) = (e^2x - 1)/(e^2x + 1); clamp |x|<=9, one shared rcp
  // per pair; |err| ~1e-6 << bf16-quant absmax 9.8e-3.
#pragma unroll
  for (int mi = 0; mi < 4; ++mi) {
#pragma unroll
    for (int ni = 0; ni < 2; ++ni) {
      f32x4 v0 = acc0[mi][ni];
      f32x4 v1 = acc1[mi][ni];
      int colLocal = wn + ni * 16 + r16;
      float bev0 = be0S[colLocal];
      float bev1 = be1S[colLocal];
#pragma unroll
      for (int r = 0; r < 4; ++r) {
        int lrow = wm + mi * 16 + g16 * 4 + r;
        if (lrow < nrow) {
          float x0 = fminf(9.f, fmaxf(-9.f, v0[r] + bev0)) * 2.885390082f;
          float x1 = fminf(9.f, fmaxf(-9.f, v1[r] + bev1)) * 2.885390082f;
          float e0v, e1v, invd;
          asm("v_exp_f32 %0, %1" : "=v"(e0v) : "v"(x0));  // 2^(2x*log2e)=e^2x
          asm("v_exp_f32 %0, %1" : "=v"(e1v) : "v"(x1));
          float d0 = e0v + 1.f, d1 = e1v + 1.f;
          asm("v_rcp_f32 %0, %1" : "=v"(invd) : "v"(d0 * d1));
          float t0 = (e0v - 1.f) * d1 * invd;
          float t1 = (e1v - 1.f) * d0 * invd;
          out[(size_t)tokS[lrow] * DOUT + c0 + colLocal] =
              t0 * w0S[lrow] + t1 * w1S[lrow];
        }
      }
    }
  }
}

extern "C" void kernel_launch(void* const* d_in, const int* in_sizes, int n_in,
                              void* d_out, int out_size, void* d_ws, size_t ws_size,
                              hipStream_t stream) {
  const float* x    = (const float*)d_in[0];
  const float* emb  = (const float*)d_in[1];
  const int*   aty  = (const int*)d_in[2];
  const float* Wg   = (const float*)d_in[3];
  const float* We   = (const float*)d_in[4];
  const float* be   = (const float*)d_in[5];
  float* out = (float*)d_out;

  char* ws = (char*)d_ws;
  int*   hpart     = (int*)(ws + WS_HPART);
  float* route_w   = (float*)(ws + WS_ROUTE_W);
  int*   base_type = (int*)(ws + WS_BASET);
  int*   cursor    = (int*)(ws + WS_CURS);
  int*   cnt_pair  = (int*)(ws + WS_CNTP);
  int*   base_pair = (int*)(ws + WS_BASEP);
  int*   ntile     = (int*)(ws + WS_NTILE);
  int*   tmap      = (int*)(ws + WS_TMAP);
  int*   row_map   = (int*)(ws + WS_RMAP);
  float* wgt       = (float*)(ws + WS_WGT);
  bf16*  xg        = (bf16*)(ws + WS_XG);
  bf16*  WeT       = (bf16*)(ws + WS_WET);

  hist_kernel<<<NTOK / 256, 256, 0, stream>>>(aty, hpart);
  route_scan_kernel<<<1, 128, 0, stream>>>(emb, Wg, hpart, route_w, base_type,
                                           cursor, cnt_pair, base_pair, ntile, tmap);
  prep_kernel<<<256 + 512, 256, 0, stream>>>(x, We, aty, route_w, base_type,
                                             cursor, row_map, wgt, xg, WeT);
  // every out element written exactly once -> no memset of out needed
  moe_gemm_pair_kernel<<<dim3(8, MAXTILE), 256, 0, stream>>>(
      xg, WeT, be, cnt_pair, base_pair, ntile, tmap, row_map, wgt, out);
}

// Round 8
// 83.440 us; speedup vs baseline: 1.8882x; 1.8882x over previous
//
#include <hip/hip_runtime.h>
#include <hip/hip_bf16.h>
#include <math.h>

typedef __bf16 bf16;
typedef __bf16 bf16x8 __attribute__((ext_vector_type(8)));
typedef float  f32x4  __attribute__((ext_vector_type(4)));

#define NTOK   16384
#define DIN    512
#define DOUT   512
#define NTYPES 128
#define TEBD   128
#define NEXP   8
#define NPAIR  64      // pair key = e0*8+e1 (e0 = top-1, e1 = top-2, always distinct)
#define MAXTILE 192    // sum_l ceil(n_l/128) <= 64 + 16384/128 = 192

// ---- workspace layout (bytes); total ~29.7 MB ----
// xgf: fragment-packed A. tile ti (128 packed rows) = 65536 bf16;
//   chunk (rowblk i in 0..7, kstep ks in 0..15) = 512 elems, LANE-ORDERED:
//   elem = ti*65536 + i*8192 + ks*512 + lane*8, lane=(row&15)+16*((k%32)>>3)
// wef: fragment-packed B per expert: chunk (e, colblk c16 in 0..31, ks):
//   elem = ((e*32+c16)*16+ks)*512 + lane*8, lane=(col&15)+16*((k%32)>>3)
#define WS_HPART   0                          // int[128][64] transposed partials
#define WS_ROUTE_W 32768                      // float2[128] (w0,w1) per type
#define WS_BASET   33792                      // int[128] packed base per type
#define WS_CURS    34304                      // int[128] per-type cursor
#define WS_CNTP    34816                      // int[64]  per-pair count
#define WS_BASEP   35072                      // int[64]  per-pair base (128-ALIGNED)
#define WS_NTILE   35328                      // int[1]
#define WS_TMAP    35840                      // int2[192] (list, r0)
#define WS_RMAP    37888                      // int[192*128] packed row -> token (pads=0)
#define WS_WGT     (WS_RMAP + MAXTILE * 128 * 4)        // float2[192*128]
#define WS_XGF     (WS_WGT + MAXTILE * 128 * 8)         // bf16, 24 MB
#define WS_WEF     (WS_XGF + (size_t)MAXTILE * 65536 * 2)  // bf16, 4 MB

// ------- per-block type histogram partials, TRANSPOSED [type][block] -------
__global__ void hist_kernel(const int* __restrict__ atype, int* __restrict__ hpart) {
  __shared__ int h[NTYPES];
  int tid = threadIdx.x;
  if (tid < NTYPES) h[tid] = 0;
  __syncthreads();
  int t = blockIdx.x * 256 + tid;
  atomicAdd(&h[atype[t]], 1);
  __syncthreads();
  if (tid < NTYPES) hpart[tid * 64 + blockIdx.x] = h[tid];
}

// ---- route (top-2 softmax per type) + pair scan + tile map, one block -----
// base_pair is 128-ALIGNED so packed tile ti <-> rows [ti*128, ti*128+128)
// and the fragment-packed xgf tile index is simply ti. Pad rows get
// row_map=0 (token 0: valid data, masked in the GEMM epilogue by nrow).
__global__ void route_scan_kernel(const float* __restrict__ emb,
                                  const float* __restrict__ Wg,
                                  const int* __restrict__ hpart,
                                  float* __restrict__ route_w,
                                  int* __restrict__ base_type,
                                  int* __restrict__ cursor,
                                  int* __restrict__ cnt_pair,
                                  int* __restrict__ base_pair,
                                  int* __restrict__ ntile,
                                  int* __restrict__ tmap,
                                  int* __restrict__ row_map) {
  __shared__ int s_cnt[NPAIR];
  __shared__ int s_off[NTYPES];
  __shared__ int s_pair[NTYPES];
  int t = threadIdx.x;  // 128 threads = 128 types
  if (t < NPAIR) s_cnt[t] = 0;
  __syncthreads();

  int myc = 0;
  {
    const int4* hp = (const int4*)(hpart + t * 64);
#pragma unroll
    for (int b = 0; b < 16; ++b) {
      int4 v = hp[b];
      myc += v.x + v.y + v.z + v.w;
    }
  }

  const float* er = emb + (size_t)t * TEBD;
  float lg[NEXP];
#pragma unroll
  for (int e = 0; e < NEXP; ++e) lg[e] = 0.f;
  for (int j = 0; j < TEBD; ++j) {
    float ev = er[j];
#pragma unroll
    for (int e = 0; e < NEXP; ++e) lg[e] += ev * Wg[j * NEXP + e];
  }
  float v0 = -__builtin_inff(), v1 = -__builtin_inff();
  int i0 = 0, i1 = 0;
#pragma unroll
  for (int e = 0; e < NEXP; ++e) {
    float v = lg[e];
    if (v > v0) { v1 = v0; i1 = i0; v0 = v; i0 = e; }
    else if (v > v1) { v1 = v; i1 = e; }
  }
  float d = expf(v1 - v0);
  float inv = 1.f / (1.f + d);
  route_w[t * 2 + 0] = inv;
  route_w[t * 2 + 1] = d * inv;
  int p = i0 * 8 + i1;
  s_pair[t] = p;
  s_off[t] = atomicAdd(&s_cnt[p], myc);
  cursor[t] = 0;
  __syncthreads();

  if (t < NPAIR) {
    int b = 0, tb = 0;
    for (int j = 0; j < t; ++j) {
      int nt_j = (s_cnt[j] + 127) >> 7;
      b += nt_j << 7;          // 128-aligned cumulative base
      tb += nt_j;
    }
    base_pair[t] = b;
    cnt_pair[t] = s_cnt[t];
    int nt_l = (s_cnt[t] + 127) >> 7;
    for (int i = 0; i < nt_l; ++i) {
      tmap[(tb + i) * 2 + 0] = t;
      tmap[(tb + i) * 2 + 1] = i * 128;
    }
    // pad rows of this list -> token 0 (gather then reads valid x row)
    for (int i = s_cnt[t]; i < (nt_l << 7); ++i) row_map[b + i] = 0;
    if (t == NPAIR - 1) ntile[0] = tb + nt_l;
  }
  __syncthreads();
  base_type[t] = base_pair[s_pair[t]] + s_off[t];
}

// ------------- place: token -> packed row (row_map, wgt) -------------------
__global__ void place_kernel(const int* __restrict__ atype,
                             const float* __restrict__ route_w,
                             const int* __restrict__ base_type,
                             int* __restrict__ cursor,
                             int* __restrict__ row_map,
                             float* __restrict__ wgt) {
  __shared__ int lc[NTYPES];
  __shared__ int lb[NTYPES];
  int tid = threadIdx.x;
  if (tid < NTYPES) lc[tid] = 0;
  __syncthreads();
  int t = blockIdx.x * 256 + tid;
  int ty = atype[t];
  int r = atomicAdd(&lc[ty], 1);
  __syncthreads();
  if (tid < NTYPES) lb[tid] = lc[tid] ? atomicAdd(&cursor[tid], lc[tid]) : 0;
  __syncthreads();
  int pos = base_type[ty] + lb[ty] + r;
  row_map[pos] = t;
  ((float2*)wgt)[pos] = ((const float2*)route_w)[ty];
}

// ---- fragment-pack: xgf (blocks 0..383, half-tiles) | wef (blocks 384..895)
__global__ void gatherweT_kernel(const float* __restrict__ x,
                                 const float* __restrict__ We,
                                 const int* __restrict__ ntile,
                                 const int* __restrict__ row_map,
                                 bf16* __restrict__ xgf,
                                 bf16* __restrict__ wef) {
  int bx = blockIdx.x;
  int tid = threadIdx.x;
  if (bx < 384) {
    // ---- gather + cvt + fragment-pack 64 packed rows (half a tile) ----
    if (bx * 64 >= ntile[0] * 128) return;  // beyond live tiles
    int tile = bx >> 1;
    int w = tid >> 6, lane = tid & 63;
    int r16 = lane & 15, kk = lane >> 4;
    int i = (bx & 1) * 4 + w;               // rowblk 0..7 within tile
    int row = tile * 128 + i * 16 + r16;
    int tok = row_map[row];
    const float* xr = x + (size_t)tok * DIN + kk * 8;
    bf16* dst = xgf + (size_t)tile * 65536 + i * 8192 + lane * 8;
    // writes: 64 lanes x 16B contiguous = 1KB coalesced per ks
#pragma unroll
    for (int ks = 0; ks < 16; ++ks) {
      const float4* p = (const float4*)(xr + ks * 32);
      float4 a = p[0], b = p[1];
      bf16x8 o;
      o[0] = (bf16)a.x; o[1] = (bf16)a.y; o[2] = (bf16)a.z; o[3] = (bf16)a.w;
      o[4] = (bf16)b.x; o[5] = (bf16)b.y; o[6] = (bf16)b.z; o[7] = (bf16)b.w;
      *(bf16x8*)(dst + ks * 512) = o;
    }
  } else {
    // ---- We[e][k][n] f32 -> wef fragment-packed bf16, 64x64 tiles ----
    __shared__ float t[64][65];
    int b2 = bx - 384;        // 512 = 8 experts * 8(kt) * 8(nt)
    int e = b2 >> 6;
    int rem = b2 & 63;
    int kt = (rem >> 3) * 64;
    int nt = (rem & 7) * 64;
    int col = tid & 63;
    int rq = tid >> 6;
#pragma unroll
    for (int r = 0; r < 16; ++r) {
      int krow = rq * 16 + r;
      t[krow][col] = We[((size_t)e * DIN + kt + krow) * DOUT + nt + col];
    }
    __syncthreads();
    int lane = tid & 63;
    int c16 = (nt >> 4) + rq;               // global col-block16 (wave-owned)
    int colL = rq * 16 + (lane & 15);       // col within the 64-tile
    int kk = lane >> 4;
#pragma unroll
    for (int ksl = 0; ksl < 2; ++ksl) {
      int ks = (kt >> 5) + ksl;
      bf16x8 o;
#pragma unroll
      for (int j = 0; j < 8; ++j) o[j] = (bf16)t[ksl * 32 + kk * 8 + j][colL];
      *(bf16x8*)(wef + ((size_t)(e * 32 + c16) * 16 + ks) * 512 + lane * 8) = o;
    }
  }
}

// --------- pair-merged grouped GEMM: register-direct, COALESCED ------------
// Round-8: R7's no-LDS loop was right about the bottleneck (2-phase
// barrier-chain wall: all pipes <=25%, every schedule knob flat) but died on
// uncoalesced fragment loads (16 scattered lines/instr). Now xgf/wef are
// PRE-PACKED in MFMA fragment order: every fragment load is ONE contiguous
// 1KB global_load_dwordx4 from L2/L3. Zero barriers in the main loop, zero
// LDS staging, register ping-pong 2 k-steps deep, compiler-placed waitcnts,
// 3 blocks/CU. tile: BM=128 x BN=64 x 2 experts, 4 waves (2x2).
__global__ __launch_bounds__(256, 3) void moe_gemm_pair_kernel(
    const bf16* __restrict__ xgf, const bf16* __restrict__ wef,
    const float* __restrict__ be, const int* __restrict__ cnt_pair,
    const int* __restrict__ ntile, const int* __restrict__ tmap,
    const int* __restrict__ row_map, const float* __restrict__ wgt,
    float* __restrict__ out) {
  int nwork = ntile[0] * 8;
  int f = blockIdx.y * 8 + blockIdx.x;
  if (f >= nwork) return;
  // bijective chunked XCD swizzle (L2 locality for shared A/B panels)
  int q = nwork >> 3, r = nwork & 7;
  int xcd = f & 7, idx = f >> 3;
  int L = (xcd < r ? xcd * (q + 1) : r * (q + 1) + (xcd - r) * q) + idx;
  int ti = L >> 3;
  int cx = L & 7;
  int list = tmap[ti * 2 + 0];
  int r0   = tmap[ti * 2 + 1];
  int e0 = list >> 3, e1 = list & 7;
  int nrow = cnt_pair[list] - r0;
  if (nrow > 128) nrow = 128;
  int c0 = cx * 64;
  int arow0 = ti * 128;     // base_pair is 128-aligned

  __shared__ int   tokS[128];
  __shared__ float w0S[128], w1S[128];
  __shared__ float be0S[64], be1S[64];

  int tid = threadIdx.x;
  int lane = tid & 63, w = tid >> 6;

  // epilogue metadata -> LDS (single barrier before epilogue orders it)
  if (tid < 128) {
    int srow = (tid < nrow) ? tid : (nrow - 1);
    int gl = arow0 + srow;
    tokS[tid] = row_map[gl];
    float2 ww = ((const float2*)wgt)[gl];
    w0S[tid] = ww.x;
    w1S[tid] = ww.y;
    if (tid < 64) {
      be0S[tid] = be[e0 * DOUT + c0 + tid];
      be1S[tid] = be[e1 * DOUT + c0 + tid];
    }
  }

  int wm = (w >> 1) * 64;
  int wn = (w & 1) * 32;
  int r16 = lane & 15, g16 = lane >> 4;

  // fragment base pointers: lane*16B inside a 1KB lane-ordered chunk.
  // k-step ks adds ks*1024B (compile-time).
  const bf16* pA[4];
#pragma unroll
  for (int mi = 0; mi < 4; ++mi)
    pA[mi] = xgf + (size_t)ti * 65536 + ((w >> 1) * 4 + mi) * 8192 + lane * 8;
  const bf16* pB0[2];
  const bf16* pB1[2];
#pragma unroll
  for (int ni = 0; ni < 2; ++ni) {
    int c16 = (c0 >> 4) + (w & 1) * 2 + ni;
    pB0[ni] = wef + ((size_t)(e0 * 32 + c16) * 16) * 512 + lane * 8;
    pB1[ni] = wef + ((size_t)(e1 * 32 + c16) * 16) * 512 + lane * 8;
  }

  f32x4 acc0[4][2], acc1[4][2];
#pragma unroll
  for (int mi = 0; mi < 4; ++mi)
#pragma unroll
    for (int ni = 0; ni < 2; ++ni) { acc0[mi][ni] = (f32x4)0.f; acc1[mi][ni] = (f32x4)0.f; }

  bf16x8 aX[4], b0X[2], b1X[2];
  bf16x8 aY[4], b0Y[2], b1Y[2];

#define LOADSET(A, B0, B1, kk)                                                \
  {                                                                           \
    _Pragma("unroll") for (int i = 0; i < 4; ++i)                             \
        A[i] = *(const bf16x8*)(pA[i] + (kk) * 512);                          \
    _Pragma("unroll") for (int i = 0; i < 2; ++i)                             \
        B0[i] = *(const bf16x8*)(pB0[i] + (kk) * 512);                        \
    _Pragma("unroll") for (int i = 0; i < 2; ++i)                             \
        B1[i] = *(const bf16x8*)(pB1[i] + (kk) * 512);                        \
  }

#define MFMASET(A, B0, B1)                                                    \
  {                                                                           \
    _Pragma("unroll") for (int mi = 0; mi < 4; ++mi)                          \
        _Pragma("unroll") for (int ni = 0; ni < 2; ++ni) {                    \
      acc0[mi][ni] = __builtin_amdgcn_mfma_f32_16x16x32_bf16(                 \
          A[mi], B0[ni], acc0[mi][ni], 0, 0, 0);                              \
      acc1[mi][ni] = __builtin_amdgcn_mfma_f32_16x16x32_bf16(                 \
          A[mi], B1[ni], acc1[mi][ni], 0, 0, 0);                              \
    }                                                                         \
  }

  LOADSET(aX, b0X, b1X, 0);
  LOADSET(aY, b0Y, b1Y, 1);
#pragma unroll
  for (int t = 0; t < 16; t += 2) {
    MFMASET(aX, b0X, b1X);
    if (t + 2 < 16) LOADSET(aX, b0X, b1X, t + 2);
    MFMASET(aY, b0Y, b1Y);
    if (t + 3 < 16) LOADSET(aY, b0Y, b1Y, t + 3);
  }
#undef LOADSET
#undef MFMASET

  __syncthreads();  // order tokS/wS/beS writes before epilogue reads

  // ---- epilogue: out = w0*tanh(acc0+b0) + w1*tanh(acc1+b1), plain store ---
#pragma unroll
  for (int mi = 0; mi < 4; ++mi) {
#pragma unroll
    for (int ni = 0; ni < 2; ++ni) {
      f32x4 v0 = acc0[mi][ni];
      f32x4 v1 = acc1[mi][ni];
      int colLocal = wn + ni * 16 + r16;
      float bev0 = be0S[colLocal];
      float bev1 = be1S[colLocal];
#pragma unroll
      for (int r = 0; r < 4; ++r) {
        int lrow = wm + mi * 16 + g16 * 4 + r;
        if (lrow < nrow) {
          float x0 = fminf(9.f, fmaxf(-9.f, v0[r] + bev0)) * 2.885390082f;
          float x1 = fminf(9.f, fmaxf(-9.f, v1[r] + bev1)) * 2.885390082f;
          float e0v, e1v, invd;
          asm("v_exp_f32 %0, %1" : "=v"(e0v) : "v"(x0));  // 2^(2x*log2e)=e^2x
          asm("v_exp_f32 %0, %1" : "=v"(e1v) : "v"(x1));
          float d0 = e0v + 1.f, d1 = e1v + 1.f;
          asm("v_rcp_f32 %0, %1" : "=v"(invd) : "v"(d0 * d1));
          float t0 = (e0v - 1.f) * d1 * invd;
          float t1 = (e1v - 1.f) * d0 * invd;
          out[(size_t)tokS[lrow] * DOUT + c0 + colLocal] =
              t0 * w0S[lrow] + t1 * w1S[lrow];
        }
      }
    }
  }
}

extern "C" void kernel_launch(void* const* d_in, const int* in_sizes, int n_in,
                              void* d_out, int out_size, void* d_ws, size_t ws_size,
                              hipStream_t stream) {
  const float* x    = (const float*)d_in[0];
  const float* emb  = (const float*)d_in[1];
  const int*   aty  = (const int*)d_in[2];
  const float* Wg   = (const float*)d_in[3];
  const float* We   = (const float*)d_in[4];
  const float* be   = (const float*)d_in[5];
  float* out = (float*)d_out;

  char* ws = (char*)d_ws;
  int*   hpart     = (int*)(ws + WS_HPART);
  float* route_w   = (float*)(ws + WS_ROUTE_W);
  int*   base_type = (int*)(ws + WS_BASET);
  int*   cursor    = (int*)(ws + WS_CURS);
  int*   cnt_pair  = (int*)(ws + WS_CNTP);
  int*   base_pair = (int*)(ws + WS_BASEP);
  int*   ntile     = (int*)(ws + WS_NTILE);
  int*   tmap      = (int*)(ws + WS_TMAP);
  int*   row_map   = (int*)(ws + WS_RMAP);
  float* wgt       = (float*)(ws + WS_WGT);
  bf16*  xgf       = (bf16*)(ws + WS_XGF);
  bf16*  wef       = (bf16*)(ws + WS_WEF);

  hist_kernel<<<NTOK / 256, 256, 0, stream>>>(aty, hpart);
  route_scan_kernel<<<1, 128, 0, stream>>>(emb, Wg, hpart, route_w, base_type,
                                           cursor, cnt_pair, base_pair, ntile,
                                           tmap, row_map);
  place_kernel<<<NTOK / 256, 256, 0, stream>>>(aty, route_w, base_type, cursor,
                                               row_map, wgt);
  gatherweT_kernel<<<384 + 512, 256, 0, stream>>>(x, We, ntile, row_map, xgf, wef);
  // every out element written exactly once -> no memset of out needed
  moe_gemm_pair_kernel<<<dim3(8, MAXTILE), 256, 0, stream>>>(
      xgf, wef, be, cnt_pair, ntile, tmap, row_map, wgt, out);
}

// Round 9
// 74.826 us; speedup vs baseline: 2.1056x; 1.1151x over previous
//
#include <hip/hip_runtime.h>
#include <hip/hip_bf16.h>
#include <math.h>

typedef __bf16 bf16;
typedef __bf16 bf16x8 __attribute__((ext_vector_type(8)));
typedef float  f32x4  __attribute__((ext_vector_type(4)));

#define NTOK   16384
#define DIN    512
#define DOUT   512
#define NTYPES 128
#define TEBD   128
#define NEXP   8
#define NPAIR  64      // pair key = e0*8+e1 (e0 = top-1, e1 = top-2, always distinct)
#define MAXTILE 192    // sum_l ceil(n_l/128) <= 64 + 16384/128 = 192

// ---- workspace layout (bytes); total ~20.5 MB ----
#define WS_HPART   0                          // int[128][64] transposed partials (32KB)
#define WS_ROUTE_W 32768                      // float2[128] (w0,w1) per type
#define WS_BASET   33792                      // int[128] packed base per type
#define WS_CURS    34304                      // int[128] per-type cursor
#define WS_CNTP    34816                      // int[64]  per-pair count
#define WS_BASEP   35072                      // int[64]  per-pair base (128-ALIGNED)
#define WS_NTILE   35328                      // int[1]
#define WS_TMAP    35840                      // int2[192] (list, r0)
#define WS_RMAP    37888                      // int[192*128] packed row -> token (pads=0)
#define WS_WGT     (WS_RMAP + MAXTILE * 128 * 4)   // float2[192*128]
#define WS_XB      (WS_WGT + MAXTILE * 128 * 8)    // bf16[16384*512] LINEAR x (16 MB)
#define WS_WET     (WS_XB + (size_t)NTOK * DIN * 2)  // bf16[8*512*512] (4 MB)

#define GLOAD_LDS16(g, l)                                                     \
  __builtin_amdgcn_global_load_lds(                                           \
      (const __attribute__((address_space(1))) void*)(g),                     \
      (__attribute__((address_space(3))) void*)(l), 16, 0, 0)

// ---- fused prep, 3 independent block ranges (all routing-independent) -----
// [0,64):    per-block type-hist partials, transposed hpart[type][block]
// [64,576):  We[e][k][n] f32 -> WeT[e][n][k] bf16 (64x64 tiles)
// [576,2624): x f32 -> xb bf16, LINEAR (no gather -- R8 showed the packed
//            gather round-trip (24MB write + 30MB cold read + a dispatch)
//            buys nothing: scattered-row staging in the GEMM is same-speed)
__global__ void fused_prep_kernel(const float* __restrict__ x,
                                  const float* __restrict__ We,
                                  const int* __restrict__ atype,
                                  int* __restrict__ hpart,
                                  bf16* __restrict__ xb,
                                  bf16* __restrict__ WeT) {
  int bx = blockIdx.x;
  int tid = threadIdx.x;
  if (bx < 64) {
    __shared__ int h[NTYPES];
    if (tid < NTYPES) h[tid] = 0;
    __syncthreads();
    int t = bx * 256 + tid;
    atomicAdd(&h[atype[t]], 1);
    __syncthreads();
    if (tid < NTYPES) hpart[tid * 64 + bx] = h[tid];
  } else if (bx < 576) {
    __shared__ float t[64][65];
    int b2 = bx - 64;         // 512 = 8 experts * 8 * 8 tiles
    int e = b2 >> 6;
    int rem = b2 & 63;
    int kt = (rem >> 3) * 64;
    int nt = (rem & 7) * 64;
    int col = tid & 63;
    int rq = tid >> 6;
#pragma unroll
    for (int r = 0; r < 16; ++r) {
      int row = rq * 16 + r;
      t[row][col] = We[((size_t)e * DIN + kt + row) * DOUT + nt + col];
    }
    __syncthreads();
#pragma unroll
    for (int r = 0; r < 16; ++r) {
      int n = rq * 16 + r;
      WeT[((size_t)e * DOUT + nt + n) * DIN + kt + col] = (bf16)t[col][n];
    }
  } else {
    // 2048 blocks x 256 threads x 16 f32 = 8.4M elements
    size_t base = (size_t)(bx - 576) * 4096 + tid * 16;
    const float4* p = (const float4*)(x + base);
    float4 a0 = p[0], a1 = p[1], a2 = p[2], a3 = p[3];
    bf16x8 o0, o1;
    o0[0] = (bf16)a0.x; o0[1] = (bf16)a0.y; o0[2] = (bf16)a0.z; o0[3] = (bf16)a0.w;
    o0[4] = (bf16)a1.x; o0[5] = (bf16)a1.y; o0[6] = (bf16)a1.z; o0[7] = (bf16)a1.w;
    o1[0] = (bf16)a2.x; o1[1] = (bf16)a2.y; o1[2] = (bf16)a2.z; o1[3] = (bf16)a2.w;
    o1[4] = (bf16)a3.x; o1[5] = (bf16)a3.y; o1[6] = (bf16)a3.z; o1[7] = (bf16)a3.w;
    *(bf16x8*)(xb + base) = o0;
    *(bf16x8*)(xb + base + 8) = o1;
  }
}

// ---- route (top-2 softmax per type) + pair scan + tile map, one block -----
// base_pair is 128-ALIGNED so packed tile ti <-> rows [ti*128, ti*128+128).
// Pad rows get row_map=0 (token 0: valid data, masked by nrow in epilogue).
__global__ void route_scan_kernel(const float* __restrict__ emb,
                                  const float* __restrict__ Wg,
                                  const int* __restrict__ hpart,
                                  float* __restrict__ route_w,
                                  int* __restrict__ base_type,
                                  int* __restrict__ cursor,
                                  int* __restrict__ cnt_pair,
                                  int* __restrict__ base_pair,
                                  int* __restrict__ ntile,
                                  int* __restrict__ tmap,
                                  int* __restrict__ row_map) {
  __shared__ int s_cnt[NPAIR];
  __shared__ int s_off[NTYPES];
  __shared__ int s_pair[NTYPES];
  int t = threadIdx.x;  // 128 threads = 128 types
  if (t < NPAIR) s_cnt[t] = 0;
  __syncthreads();

  int myc = 0;
  {
    const int4* hp = (const int4*)(hpart + t * 64);
#pragma unroll
    for (int b = 0; b < 16; ++b) {
      int4 v = hp[b];
      myc += v.x + v.y + v.z + v.w;
    }
  }

  const float* er = emb + (size_t)t * TEBD;
  float lg[NEXP];
#pragma unroll
  for (int e = 0; e < NEXP; ++e) lg[e] = 0.f;
  for (int j = 0; j < TEBD; ++j) {
    float ev = er[j];
#pragma unroll
    for (int e = 0; e < NEXP; ++e) lg[e] += ev * Wg[j * NEXP + e];
  }
  float v0 = -__builtin_inff(), v1 = -__builtin_inff();
  int i0 = 0, i1 = 0;
#pragma unroll
  for (int e = 0; e < NEXP; ++e) {
    float v = lg[e];
    if (v > v0) { v1 = v0; i1 = i0; v0 = v; i0 = e; }
    else if (v > v1) { v1 = v; i1 = e; }
  }
  float d = expf(v1 - v0);
  float inv = 1.f / (1.f + d);
  route_w[t * 2 + 0] = inv;
  route_w[t * 2 + 1] = d * inv;
  int p = i0 * 8 + i1;
  s_pair[t] = p;
  s_off[t] = atomicAdd(&s_cnt[p], myc);
  cursor[t] = 0;
  __syncthreads();

  if (t < NPAIR) {
    int b = 0, tb = 0;
    for (int j = 0; j < t; ++j) {
      int nt_j = (s_cnt[j] + 127) >> 7;
      b += nt_j << 7;          // 128-aligned cumulative base
      tb += nt_j;
    }
    base_pair[t] = b;
    cnt_pair[t] = s_cnt[t];
    int nt_l = (s_cnt[t] + 127) >> 7;
    for (int i = 0; i < nt_l; ++i) {
      tmap[(tb + i) * 2 + 0] = t;
      tmap[(tb + i) * 2 + 1] = i * 128;
    }
    for (int i = s_cnt[t]; i < (nt_l << 7); ++i) row_map[b + i] = 0;
    if (t == NPAIR - 1) ntile[0] = tb + nt_l;
  }
  __syncthreads();
  base_type[t] = base_pair[s_pair[t]] + s_off[t];
}

// ------------- place: token -> packed row (row_map, wgt) — indices only ----
__global__ void place_kernel(const int* __restrict__ atype,
                             const float* __restrict__ route_w,
                             const int* __restrict__ base_type,
                             int* __restrict__ cursor,
                             int* __restrict__ row_map,
                             float* __restrict__ wgt) {
  __shared__ int lc[NTYPES];
  __shared__ int lb[NTYPES];
  int tid = threadIdx.x;
  if (tid < NTYPES) lc[tid] = 0;
  __syncthreads();
  int t = blockIdx.x * 256 + tid;
  int ty = atype[t];
  int r = atomicAdd(&lc[ty], 1);
  __syncthreads();
  if (tid < NTYPES) lb[tid] = lc[tid] ? atomicAdd(&cursor[tid], lc[tid]) : 0;
  __syncthreads();
  int pos = base_type[ty] + lb[ty] + r;
  row_map[pos] = t;
  ((float2*)wgt)[pos] = ((const float2*)route_w)[ty];
}

// --------- pair-merged grouped GEMM (R6's measured-best, scattered-A) ------
// tile: BM=128 x BN=64 x 2 experts, BK=32, 4 waves (2x2), 16x16x32 MFMA.
// DEPTH-4 pipeline: 4 LDS buffers, stage 3 ahead, steady vmcnt(8).
// A rows staged DIRECTLY from linear xb via tokS (scattered 64B/row
// segments — R1-proven same speed as packed; saves the 24MB gather
// round-trip + one dispatch). B from WeT. LDS 64KB -> 2 blocks/CU.
// Epilogue: out = w0*tanh(acc0+b0) + w1*tanh(acc1+b1) (fast exp tanh),
// plain scattered store: each token in exactly one pair list -> no
// memset, no atomics, no RMW.
__global__ __launch_bounds__(256, 2) void moe_gemm_pair_kernel(
    const bf16* __restrict__ xb, const bf16* __restrict__ WeT,
    const float* __restrict__ be, const int* __restrict__ cnt_pair,
    const int* __restrict__ ntile, const int* __restrict__ tmap,
    const int* __restrict__ row_map, const float* __restrict__ wgt,
    float* __restrict__ out) {
  int nwork = ntile[0] * 8;
  int f = blockIdx.y * 8 + blockIdx.x;
  if (f >= nwork) return;
  // bijective chunked XCD swizzle: 8 col-blocks of a row-tile stay on one
  // XCD so the scattered A rows are fetched once and L2-hit 7 times.
  int q = nwork >> 3, r = nwork & 7;
  int xcd = f & 7, idx = f >> 3;
  int L = (xcd < r ? xcd * (q + 1) : r * (q + 1) + (xcd - r) * q) + idx;
  int ti = L >> 3;
  int cx = L & 7;
  int list = tmap[ti * 2 + 0];
  int r0   = tmap[ti * 2 + 1];
  int e0 = list >> 3, e1 = list & 7;
  int nrow = cnt_pair[list] - r0;
  if (nrow > 128) nrow = 128;
  int c0 = cx * 64;
  int arow0 = ti * 128;     // base_pair is 128-aligned

  __shared__ __align__(16) bf16 As[4][128 * 32];
  __shared__ __align__(16) bf16 B0s[4][64 * 32];
  __shared__ __align__(16) bf16 B1s[4][64 * 32];
  __shared__ int   tokS[128];
  __shared__ float w0S[128], w1S[128];
  __shared__ float be0S[64], be1S[64];

  int tid = threadIdx.x;
  int lane = tid & 63, w = tid >> 6;

  // token list / weights / bias first (A staging needs tokS)
  if (tid < 128) {
    int srow = (tid < nrow) ? tid : (nrow - 1);
    tokS[tid] = row_map[arow0 + srow];
    float2 ww = ((const float2*)wgt)[arow0 + srow];
    w0S[tid] = ww.x;
    w1S[tid] = ww.y;
    if (tid < 64) {
      be0S[tid] = be[e0 * DOUT + c0 + tid];
      be1S[tid] = be[e1 * DOUT + c0 + tid];
    }
  }
  __syncthreads();

  // per-lane global sources; chunk swizzle c = cs ^ ((row>>1)&3) keeps the
  // ds_read_b128 side bank-balanced while gload_lds dest stays linear
  const bf16* srcA[2];
#pragma unroll
  for (int j = 0; j < 2; ++j) {
    int slot = w * 128 + j * 64 + lane;
    int row = slot >> 2, cs = slot & 3;
    int c = cs ^ ((row >> 1) & 3);
    srcA[j] = xb + (size_t)tokS[row] * DIN + c * 8;
  }
  const bf16* srcB0;
  const bf16* srcB1;
  {
    int slot = w * 64 + lane;
    int row = slot >> 2, cs = slot & 3;
    int c = cs ^ ((row >> 1) & 3);
    srcB0 = WeT + ((size_t)e0 * DOUT + c0 + row) * DIN + c * 8;
    srcB1 = WeT + ((size_t)e1 * DOUT + c0 + row) * DIN + c * 8;
  }

  auto stage = [&](int buf) {  // 4 gload_lds per wave, then advance one BK
#pragma unroll
    for (int j = 0; j < 2; ++j) {
      GLOAD_LDS16(srcA[j], &As[buf][(w * 128 + j * 64) * 8]);
      srcA[j] += 32;
    }
    GLOAD_LDS16(srcB0, &B0s[buf][w * 64 * 8]);
    GLOAD_LDS16(srcB1, &B1s[buf][w * 64 * 8]);
    srcB0 += 32;
    srcB1 += 32;
  };

  // prologue: 3 tiles in flight (12 loads/wave)
  stage(0);
  stage(1);
  stage(2);

  f32x4 acc0[4][2], acc1[4][2];
#pragma unroll
  for (int mi = 0; mi < 4; ++mi)
#pragma unroll
    for (int ni = 0; ni < 2; ++ni) { acc0[mi][ni] = (f32x4)0.f; acc1[mi][ni] = (f32x4)0.f; }

  int wm = (w >> 1) * 64;
  int wn = (w & 1) * 32;
  int r16 = lane & 15, g16 = lane >> 4;

  int offA[4], offB[2];
#pragma unroll
  for (int i = 0; i < 4; ++i) {
    int rA = wm + i * 16 + r16;
    offA[i] = rA * 32 + (g16 ^ ((rA >> 1) & 3)) * 8;
  }
#pragma unroll
  for (int i = 0; i < 2; ++i) {
    int rB = wn + i * 16 + r16;
    offB[i] = rB * 32 + (g16 ^ ((rB >> 1) & 3)) * 8;
  }

#pragma unroll
  for (int t = 0; t < 16; ++t) {
    // wait for tile t only; tiles t+1..t+3 stay in flight.
    if (t < 14)      asm volatile("s_waitcnt vmcnt(8)" ::: "memory");
    else if (t == 14) asm volatile("s_waitcnt vmcnt(4)" ::: "memory");
    else              asm volatile("s_waitcnt vmcnt(0)" ::: "memory");
    __builtin_amdgcn_s_barrier();
    // overwrite buf[(t+3)&3] == buf[(t-1)&3]: all waves passed the barrier,
    // hence finished their iter t-1 ds_reads (MFMA consumed them)
    if (t + 3 < 16) stage((t + 3) & 3);

    int cur = t & 3;
    bf16x8 af[4], b0f[2], b1f[2];
#pragma unroll
    for (int i = 0; i < 4; ++i) af[i] = *(const bf16x8*)&As[cur][offA[i]];
#pragma unroll
    for (int i = 0; i < 2; ++i) b0f[i] = *(const bf16x8*)&B0s[cur][offB[i]];
#pragma unroll
    for (int i = 0; i < 2; ++i) b1f[i] = *(const bf16x8*)&B1s[cur][offB[i]];
    __builtin_amdgcn_s_setprio(1);
#pragma unroll
    for (int mi = 0; mi < 4; ++mi)
#pragma unroll
      for (int ni = 0; ni < 2; ++ni) {
        acc0[mi][ni] = __builtin_amdgcn_mfma_f32_16x16x32_bf16(
            af[mi], b0f[ni], acc0[mi][ni], 0, 0, 0);
        acc1[mi][ni] = __builtin_amdgcn_mfma_f32_16x16x32_bf16(
            af[mi], b1f[ni], acc1[mi][ni], 0, 0, 0);
      }
    __builtin_amdgcn_s_setprio(0);
  }

  // ---- epilogue: out = w0*tanh(acc0+b0) + w1*tanh(acc1+b1), plain store ---
  // fast tanh: tanh(x) = (e^2x - 1)/(e^2x + 1); clamp |x|<=9, one shared rcp
  // per pair; |err| ~1e-6 << bf16-quant absmax 9.8e-3.
#pragma unroll
  for (int mi = 0; mi < 4; ++mi) {
#pragma unroll
    for (int ni = 0; ni < 2; ++ni) {
      f32x4 v0 = acc0[mi][ni];
      f32x4 v1 = acc1[mi][ni];
      int colLocal = wn + ni * 16 + r16;
      float bev0 = be0S[colLocal];
      float bev1 = be1S[colLocal];
#pragma unroll
      for (int r = 0; r < 4; ++r) {
        int lrow = wm + mi * 16 + g16 * 4 + r;
        if (lrow < nrow) {
          float x0 = fminf(9.f, fmaxf(-9.f, v0[r] + bev0)) * 2.885390082f;
          float x1 = fminf(9.f, fmaxf(-9.f, v1[r] + bev1)) * 2.885390082f;
          float e0v, e1v, invd;
          asm("v_exp_f32 %0, %1" : "=v"(e0v) : "v"(x0));  // 2^(2x*log2e)=e^2x
          asm("v_exp_f32 %0, %1" : "=v"(e1v) : "v"(x1));
          float d0 = e0v + 1.f, d1 = e1v + 1.f;
          asm("v_rcp_f32 %0, %1" : "=v"(invd) : "v"(d0 * d1));
          float t0 = (e0v - 1.f) * d1 * invd;
          float t1 = (e1v - 1.f) * d0 * invd;
          out[(size_t)tokS[lrow] * DOUT + c0 + colLocal] =
              t0 * w0S[lrow] + t1 * w1S[lrow];
        }
      }
    }
  }
}

extern "C" void kernel_launch(void* const* d_in, const int* in_sizes, int n_in,
                              void* d_out, int out_size, void* d_ws, size_t ws_size,
                              hipStream_t stream) {
  const float* x    = (const float*)d_in[0];
  const float* emb  = (const float*)d_in[1];
  const int*   aty  = (const int*)d_in[2];
  const float* Wg   = (const float*)d_in[3];
  const float* We   = (const float*)d_in[4];
  const float* be   = (const float*)d_in[5];
  float* out = (float*)d_out;

  char* ws = (char*)d_ws;
  int*   hpart     = (int*)(ws + WS_HPART);
  float* route_w   = (float*)(ws + WS_ROUTE_W);
  int*   base_type = (int*)(ws + WS_BASET);
  int*   cursor    = (int*)(ws + WS_CURS);
  int*   cnt_pair  = (int*)(ws + WS_CNTP);
  int*   base_pair = (int*)(ws + WS_BASEP);
  int*   ntile     = (int*)(ws + WS_NTILE);
  int*   tmap      = (int*)(ws + WS_TMAP);
  int*   row_map   = (int*)(ws + WS_RMAP);
  float* wgt       = (float*)(ws + WS_WGT);
  bf16*  xb        = (bf16*)(ws + WS_XB);
  bf16*  WeT       = (bf16*)(ws + WS_WET);

  // hist ∥ WeT transpose ∥ linear x->bf16, one dispatch
  fused_prep_kernel<<<2624, 256, 0, stream>>>(x, We, aty, hpart, xb, WeT);
  route_scan_kernel<<<1, 128, 0, stream>>>(emb, Wg, hpart, route_w, base_type,
                                           cursor, cnt_pair, base_pair, ntile,
                                           tmap, row_map);
  place_kernel<<<NTOK / 256, 256, 0, stream>>>(aty, route_w, base_type, cursor,
                                               row_map, wgt);
  // every out element written exactly once -> no memset of out needed
  moe_gemm_pair_kernel<<<dim3(8, MAXTILE), 256, 0, stream>>>(
      xb, WeT, be, cnt_pair, ntile, tmap, row_map, wgt, out);
}